// Round 11
// baseline (1776.116 us; speedup 1.0000x reference)
//
#include <hip/hip_runtime.h>
#include <cmath>

typedef __attribute__((ext_vector_type(8))) short bfrag;   // 8 bf16 = 4 VGPRs
typedef __attribute__((ext_vector_type(4))) float f32x4;

// ---------------------------------------------------------------- helpers
__device__ __forceinline__ float silu_f(float x) {
    return x * __builtin_amdgcn_rcpf(1.0f + __expf(-x));
}
__device__ __forceinline__ unsigned short f2bf(float f) {
    unsigned u = __float_as_uint(f);
    unsigned r = (u + 0x7fff + ((u >> 16) & 1)) >> 16;
    return (unsigned short)r;
}
__device__ __forceinline__ float bf2f(unsigned short h) {
    return __uint_as_float(((unsigned)h) << 16);
}
__device__ __forceinline__ unsigned packbf2(float lo, float hi) {
    return ((unsigned)f2bf(hi) << 16) | (unsigned)f2bf(lo);
}
__device__ __forceinline__ unsigned cvtpk2(float a, float b) {
    unsigned r;
    asm("v_cvt_pk_bf16_f32 %0, %1, %2" : "=v"(r) : "v"(a), "v"(b));
    return r;
}
__device__ __forceinline__ uint2 pk4(float a, float b, float c, float d) {
    return make_uint2(cvtpk2(a, b), cvtpk2(c, d));
}

// plain stage (outchain/gemmT)
template <int KSTEPS, int S, int NS, int ST>
__device__ __forceinline__ void mfma_stage_T(
    const unsigned short* Xs,
    const unsigned short* __restrict__ Whi, const unsigned short* __restrict__ Wlo,
    int Kdim, int arow0, int bcol0, int r16, int kg, f32x4 (&acc)[S][NS]) {
    #pragma unroll
    for (int s = 0; s < S; s++)
        #pragma unroll
        for (int ns = 0; ns < NS; ns++) acc[s][ns] = (f32x4)0.f;
    #pragma unroll
    for (int ks = 0; ks < KSTEPS; ks++) {
        int k0 = ks * 32;
        bfrag wh[NS], wl[NS];
        #pragma unroll
        for (int ns = 0; ns < NS; ns++) {
            size_t o = (size_t)(bcol0 + ns * 16 + r16) * Kdim + k0 + kg * 8;
            wh[ns] = *(const bfrag*)&Whi[o];
            wl[ns] = *(const bfrag*)&Wlo[o];
        }
        #pragma unroll
        for (int s = 0; s < S; s++) {
            bfrag xh = *(const bfrag*)&Xs[(arow0 + s * 16 + r16) * ST + k0 + kg * 8];
            #pragma unroll
            for (int ns = 0; ns < NS; ns++) {
                acc[s][ns] = __builtin_amdgcn_mfma_f32_16x16x32_bf16(wh[ns], xh, acc[s][ns], 0, 0, 0);
                acc[s][ns] = __builtin_amdgcn_mfma_f32_16x16x32_bf16(wl[ns], xh, acc[s][ns], 0, 0, 0);
            }
        }
    }
}

// pipelined stage (chain/downpath): W frags for ks+1 issued before ks's MFMAs
template <int KSTEPS, int S, int NS, int ST>
__device__ __forceinline__ void mfma_stage_pp(
    const unsigned short* Xs,
    const unsigned short* __restrict__ Whi, const unsigned short* __restrict__ Wlo,
    int Kdim, int arow0, int bcol0, int r16, int kg, f32x4 (&acc)[S][NS]) {
    bfrag wh[2][NS], wl[2][NS];
    #pragma unroll
    for (int ns = 0; ns < NS; ns++) {
        size_t o = (size_t)(bcol0 + ns * 16 + r16) * Kdim + kg * 8;
        wh[0][ns] = *(const bfrag*)&Whi[o];
        wl[0][ns] = *(const bfrag*)&Wlo[o];
    }
    #pragma unroll
    for (int s = 0; s < S; s++)
        #pragma unroll
        for (int ns = 0; ns < NS; ns++) acc[s][ns] = (f32x4)0.f;
    #pragma unroll
    for (int ks = 0; ks < KSTEPS; ks++) {
        const int cur = ks & 1, nxt = cur ^ 1;
        if (ks + 1 < KSTEPS) {
            #pragma unroll
            for (int ns = 0; ns < NS; ns++) {
                size_t o = (size_t)(bcol0 + ns * 16 + r16) * Kdim + (ks + 1) * 32 + kg * 8;
                wh[nxt][ns] = *(const bfrag*)&Whi[o];
                wl[nxt][ns] = *(const bfrag*)&Wlo[o];
            }
        }
        #pragma unroll
        for (int s = 0; s < S; s++) {
            bfrag xh = *(const bfrag*)&Xs[(arow0 + s * 16 + r16) * ST + ks * 32 + kg * 8];
            #pragma unroll
            for (int ns = 0; ns < NS; ns++) {
                acc[s][ns] = __builtin_amdgcn_mfma_f32_16x16x32_bf16(wh[cur][ns], xh, acc[s][ns], 0, 0, 0);
                acc[s][ns] = __builtin_amdgcn_mfma_f32_16x16x32_bf16(wl[cur][ns], xh, acc[s][ns], 0, 0, 0);
            }
        }
    }
}

// ---------------------------------------------------------------- rbf (E,6)
__global__ __launch_bounds__(256) void rbf_kernel(const float* __restrict__ d,
                                                  float* __restrict__ rbf, int E) {
    int e = blockIdx.x * 256 + threadIdx.x;
    if (e >= E) return;
    float x = d[e] * 0.2f;
    float env = 0.0f;
    if (x < 1.0f) {
        float x2 = x * x;
        float x5 = x2 * x2 * x;
        env = 1.0f / x + x5 * (-28.0f + x * (48.0f - 21.0f * x));
    }
    const float SQ = 0.63245553f;
    float px = 3.14159265358979f * x;
    #pragma unroll
    for (int n = 1; n <= 6; n++) {
        rbf[e * 6 + n - 1] = SQ * env * __sinf(px * (float)n);
    }
}

// ------------------------------------------- embedding precompute (1 block)
__global__ __launch_bounds__(128) void embed_pre_kernel(
    const float* __restrict__ se, const float* __restrict__ erw,
    const float* __restrict__ erb, const float* __restrict__ edw,
    float* __restrict__ HWj, float* __restrict__ HWi,
    float* __restrict__ W3, float* __restrict__ b3) {
    int c = threadIdx.x;
    for (int s = 0; s < 16; s++) {
        float aj = 0.f, ai = 0.f;
        for (int k = 0; k < 64; k++) {
            float h = se[s * 64 + k];
            aj += h * edw[k * 128 + c];
            ai += h * edw[(64 + k) * 128 + c];
        }
        HWj[s * 128 + c] = aj;
        HWi[s * 128 + c] = ai;
    }
    for (int r = 0; r < 6; r++) {
        float a = 0.f;
        for (int k = 0; k < 128; k++) a += erw[r * 128 + k] * edw[(128 + k) * 128 + c];
        W3[r * 128 + c] = a;
    }
    float a = 0.f;
    for (int k = 0; k < 128; k++) a += erb[k] * edw[(128 + k) * 128 + c];
    b3[c] = a;
}

// --------------- m (E,128) + fused outseg for output block 0
__global__ __launch_bounds__(256) void embed_kernel(
    const float* __restrict__ rbf, const int* __restrict__ species,
    const int* __restrict__ idx_i, const int* __restrict__ idx_j,
    const float* __restrict__ HWj, const float* __restrict__ HWi,
    const float* __restrict__ W3, const float* __restrict__ b3,
    const float* __restrict__ edb, const float* __restrict__ orw0,
    float* __restrict__ m, float* __restrict__ atom1) {
    int gid = blockIdx.x * 256 + threadIdx.x;
    int e = gid >> 7, c = gid & 127;
    int sj = species[idx_j[e]];
    int si = species[idx_i[e]];
    float rv[6];
    #pragma unroll
    for (int k = 0; k < 6; k++) rv[k] = rbf[e * 6 + k];
    float v = HWj[sj * 128 + c] + HWi[si * 128 + c] + b3[c] + edb[c];
    #pragma unroll
    for (int k = 0; k < 6; k++) v += rv[k] * W3[k * 128 + c];
    v = silu_f(v);
    m[gid] = v;
    float sc = 0.f;
    #pragma unroll
    for (int k = 0; k < 6; k++) sc += rv[k] * orw0[k * 128 + c];
    atomicAdd(&atom1[(size_t)idx_i[e] * 128 + c], sc * v);
}

// -------------------------------------- weight transpose+split (batched)
__global__ __launch_bounds__(256) void wconv_kernel(
    const float* __restrict__ W, unsigned short* __restrict__ hi,
    unsigned short* __restrict__ lo, int K, int N) {
    __shared__ float t[32][33];
    int b = blockIdx.z;
    int n0 = blockIdx.x * 32, k0 = blockIdx.y * 32;
    const float* Wb = W + (size_t)b * K * N;
    int tid = threadIdx.x;
    int r = tid >> 3, cg = tid & 7;
    float4 v = *(const float4*)&Wb[(size_t)(k0 + r) * N + n0 + cg * 4];
    t[r][cg * 4 + 0] = v.x;
    t[r][cg * 4 + 1] = v.y;
    t[r][cg * 4 + 2] = v.z;
    t[r][cg * 4 + 3] = v.w;
    __syncthreads();
    int nl = tid >> 3, kg = tid & 7;
    short4 h4, l4;
    float f0 = t[kg * 4 + 0][nl], f1 = t[kg * 4 + 1][nl];
    float f2 = t[kg * 4 + 2][nl], f3 = t[kg * 4 + 3][nl];
    unsigned short h;
    h = f2bf(f0); h4.x = (short)h; l4.x = (short)f2bf(f0 - bf2f(h));
    h = f2bf(f1); h4.y = (short)h; l4.y = (short)f2bf(f1 - bf2f(h));
    h = f2bf(f2); h4.z = (short)h; l4.z = (short)f2bf(f2 - bf2f(h));
    h = f2bf(f3); h4.w = (short)h; l4.w = (short)f2bf(f3 - bf2f(h));
    size_t o = ((size_t)b * N + n0 + nl) * K + k0 + kg * 4;
    *(short4*)&hi[o] = h4;
    *(short4*)&lo[o] = l4;
}

// --------------------- transposed-output dense GEMM, BM=64 tile
template <int ACT, int BIAS, int RES>
__global__ __launch_bounds__(512, 4) void mfma_gemmT(
    const float* __restrict__ X, const unsigned short* __restrict__ Whi,
    const unsigned short* __restrict__ Wlo,
    const float* __restrict__ bias, const float* __restrict__ resid,
    float* __restrict__ Y, int M, int K, int N) {
    __shared__ unsigned short Xs[64 * 40];
    int tid = threadIdx.x;
    int bm = blockIdx.x * 64, bn = blockIdx.y * 128;
    int wid = tid >> 6, lane = tid & 63;
    int wr = wid >> 2, wc = wid & 3;
    int r16 = lane & 15, kg = lane >> 4;
    int arow0 = wr * 32, bcol0 = wc * 32;

    f32x4 acc[2][2];
    #pragma unroll
    for (int s = 0; s < 2; s++)
        #pragma unroll
        for (int ns = 0; ns < 2; ns++) acc[s][ns] = (f32x4)0.f;

    for (int k0 = 0; k0 < K; k0 += 32) {
        {
            int row = tid >> 3, cg = tid & 7;
            float4 v = *(const float4*)&X[(size_t)(bm + row) * K + k0 + cg * 4];
            *(uint2*)&Xs[row * 40 + cg * 4] = pk4(v.x, v.y, v.z, v.w);
        }
        __syncthreads();
        bfrag wh[2], wl[2];
        #pragma unroll
        for (int ns = 0; ns < 2; ns++) {
            size_t o = (size_t)(bn + bcol0 + ns * 16 + r16) * K + k0 + kg * 8;
            wh[ns] = *(const bfrag*)&Whi[o];
            wl[ns] = *(const bfrag*)&Wlo[o];
        }
        #pragma unroll
        for (int s = 0; s < 2; s++) {
            bfrag xh = *(const bfrag*)&Xs[(arow0 + s * 16 + r16) * 40 + kg * 8];
            #pragma unroll
            for (int ns = 0; ns < 2; ns++) {
                acc[s][ns] = __builtin_amdgcn_mfma_f32_16x16x32_bf16(wh[ns], xh, acc[s][ns], 0, 0, 0);
                acc[s][ns] = __builtin_amdgcn_mfma_f32_16x16x32_bf16(wl[ns], xh, acc[s][ns], 0, 0, 0);
            }
        }
        __syncthreads();
    }
    #pragma unroll
    for (int s = 0; s < 2; s++) {
        int mm = bm + arow0 + s * 16 + r16;
        #pragma unroll
        for (int ns = 0; ns < 2; ns++) {
            int n0 = bn + bcol0 + ns * 16 + kg * 4;
            float bv[4] = {0.f, 0.f, 0.f, 0.f};
            if (BIAS) {
                float4 b4 = *(const float4*)&bias[n0];
                bv[0] = b4.x; bv[1] = b4.y; bv[2] = b4.z; bv[3] = b4.w;
            }
            float4 o;
            float* op = (float*)&o;
            #pragma unroll
            for (int r = 0; r < 4; r++) {
                float v = acc[s][ns][r] + bv[r];
                if (ACT) v = silu_f(v);
                op[r] = v;
            }
            if (RES) {
                float4 rv = *(const float4*)&resid[(size_t)mm * N + n0];
                o.x += rv.x; o.y += rv.y; o.z += rv.z; o.w += rv.w;
            }
            *(float4*)&Y[(size_t)mm * N + n0] = o;
        }
    }
}

// ---------- fused out-block tail: 3x dense(256,silu) + dot(final_w) ------
__global__ __launch_bounds__(512, 4) void outchain_kernel(
    const float* __restrict__ atom2,
    const unsigned short* __restrict__ odh, const unsigned short* __restrict__ odl,
    const float* __restrict__ odb, const float* __restrict__ wf,
    float* __restrict__ out) {
    __shared__ unsigned short Xs[64 * 264];
    __shared__ float rsum[64];
    int tid = threadIdx.x, bm = blockIdx.x * 64;
    int wid = tid >> 6, lane = tid & 63;
    int wr = wid >> 2, wc = wid & 3;
    int r16 = lane & 15, kg = lane >> 4;
    int arow0 = wr * 32, bcol0 = wc * 64;
    if (tid < 64) rsum[tid] = 0.f;

    #pragma unroll
    for (int p = 0; p < 8; p++) {
        int idx = tid + p * 512, row = idx >> 6, cg = idx & 63;
        float4 v = *(const float4*)&atom2[(size_t)(bm + row) * 256 + cg * 4];
        *(uint2*)&Xs[row * 264 + cg * 4] = pk4(v.x, v.y, v.z, v.w);
    }
    __syncthreads();

    f32x4 acc[2][4];
    #pragma unroll
    for (int st = 0; st < 3; st++) {
        mfma_stage_T<8, 2, 4, 264>(Xs, odh + (size_t)st * 65536, odl + (size_t)st * 65536,
                                   256, arow0, bcol0, r16, kg, acc);
        const float* bb = odb + st * 256;
        __syncthreads();
        if (st < 2) {
            #pragma unroll
            for (int s = 0; s < 2; s++)
                #pragma unroll
                for (int ns = 0; ns < 4; ns++) {
                    int n0 = bcol0 + ns * 16 + kg * 4;
                    float4 b4 = *(const float4*)&bb[n0];
                    *(uint2*)&Xs[(arow0 + s * 16 + r16) * 264 + n0] =
                        pk4(silu_f(acc[s][ns][0] + b4.x), silu_f(acc[s][ns][1] + b4.y),
                            silu_f(acc[s][ns][2] + b4.z), silu_f(acc[s][ns][3] + b4.w));
                }
            __syncthreads();
        } else {
            #pragma unroll
            for (int s = 0; s < 2; s++) {
                float part = 0.f;
                #pragma unroll
                for (int ns = 0; ns < 4; ns++) {
                    int n0 = bcol0 + ns * 16 + kg * 4;
                    float4 b4 = *(const float4*)&bb[n0];
                    float4 w4 = *(const float4*)&wf[n0];
                    part += silu_f(acc[s][ns][0] + b4.x) * w4.x;
                    part += silu_f(acc[s][ns][1] + b4.y) * w4.y;
                    part += silu_f(acc[s][ns][2] + b4.z) * w4.z;
                    part += silu_f(acc[s][ns][3] + b4.w) * w4.w;
                }
                atomicAdd(&rsum[arow0 + s * 16 + r16], part);
            }
        }
    }
    __syncthreads();
    if (tid < 64) out[bm + tid] += rsum[tid];
}

// =================== fused down path (BM=128): x_ji, gated x_kj, xdown ====
__global__ __launch_bounds__(512, 4) void downpath_kernel(
    const float* __restrict__ m, const float* __restrict__ rbf,
    const float* __restrict__ rbf1, const float* __restrict__ rbf2,
    const unsigned short* __restrict__ jih, const unsigned short* __restrict__ jil,
    const float* __restrict__ jib,
    const unsigned short* __restrict__ kjh, const unsigned short* __restrict__ kjl,
    const float* __restrict__ kjb,
    const unsigned short* __restrict__ dnh, const unsigned short* __restrict__ dnl,
    float* __restrict__ xji, float* __restrict__ xdown) {
    __shared__ unsigned short XsA[128 * 136];
    __shared__ unsigned short XsB[128 * 136];
    __shared__ float G8t[8][128];
    __shared__ float Rs[8][128];
    int tid = threadIdx.x, bm = blockIdx.x * 128;
    int wid = tid >> 6, lane = tid & 63;
    int wr = wid >> 2, wc = wid & 3;
    int r16 = lane & 15, kg = lane >> 4;
    int arow0 = wr * 64, bcol0 = wc * 32;

    #pragma unroll
    for (int p = 0; p < 8; p++) {
        int idx = tid + p * 512, row = idx >> 5, cg = idx & 31;
        float4 v = *(const float4*)&m[(size_t)(bm + row) * 128 + cg * 4];
        *(uint2*)&XsA[row * 136 + cg * 4] = pk4(v.x, v.y, v.z, v.w);
    }
    if (tid < 128) {
        float rv[6];
        #pragma unroll
        for (int k = 0; k < 6; k++) rv[k] = rbf[(size_t)(bm + tid) * 6 + k];
        #pragma unroll
        for (int p = 0; p < 8; p++) {
            float a = 0.f;
            #pragma unroll
            for (int k = 0; k < 6; k++) a += rv[k] * rbf1[k * 8 + p];
            G8t[p][tid] = a;
        }
    }
    for (int i = tid; i < 1024; i += 512) Rs[i >> 7][i & 127] = rbf2[i];
    __syncthreads();

    f32x4 acc[4][2];
    // ---- x_ji
    mfma_stage_pp<4, 4, 2, 136>(XsA, jih, jil, 128, arow0, bcol0, r16, kg, acc);
    #pragma unroll
    for (int s = 0; s < 4; s++) {
        int mm = bm + arow0 + s * 16 + r16;
        #pragma unroll
        for (int ns = 0; ns < 2; ns++) {
            int n0 = bcol0 + ns * 16 + kg * 4;
            float4 b4 = *(const float4*)&jib[n0];
            float4 o;
            o.x = silu_f(acc[s][ns][0] + b4.x);
            o.y = silu_f(acc[s][ns][1] + b4.y);
            o.z = silu_f(acc[s][ns][2] + b4.z);
            o.w = silu_f(acc[s][ns][3] + b4.w);
            *(float4*)&xji[(size_t)mm * 128 + n0] = o;
        }
    }
    // ---- x_kj gated -> B
    mfma_stage_pp<4, 4, 2, 136>(XsA, kjh, kjl, 128, arow0, bcol0, r16, kg, acc);
    #pragma unroll
    for (int s = 0; s < 4; s++) {
        int mrow = arow0 + s * 16 + r16;
        float g8v[8];
        #pragma unroll
        for (int p = 0; p < 8; p++) g8v[p] = G8t[p][mrow];
        #pragma unroll
        for (int ns = 0; ns < 2; ns++) {
            int n0 = bcol0 + ns * 16 + kg * 4;
            float4 b4 = *(const float4*)&kjb[n0];
            float bb[4] = {b4.x, b4.y, b4.z, b4.w};
            float v[4];
            #pragma unroll
            for (int r = 0; r < 4; r++) {
                float g = 0.f;
                #pragma unroll
                for (int p = 0; p < 8; p++) g = fmaf(g8v[p], Rs[p][n0 + r], g);
                v[r] = silu_f(acc[s][ns][r] + bb[r]) * g;
            }
            *(uint2*)&XsB[mrow * 136 + n0] = pk4(v[0], v[1], v[2], v[3]);
        }
    }
    __syncthreads();
    // ---- xdown (N=64)
    {
        int wr2 = wid >> 1, wc2 = wid & 1;
        int ar2 = wr2 * 32, bc2 = wc2 * 32;
        f32x4 a2[2][2];
        mfma_stage_pp<4, 2, 2, 136>(XsB, dnh, dnl, 128, ar2, bc2, r16, kg, a2);
        #pragma unroll
        for (int s = 0; s < 2; s++) {
            int mm = bm + ar2 + s * 16 + r16;
            #pragma unroll
            for (int ns = 0; ns < 2; ns++) {
                int n0 = bc2 + ns * 16 + kg * 4;
                float4 o;
                o.x = silu_f(a2[s][ns][0]);
                o.y = silu_f(a2[s][ns][1]);
                o.z = silu_f(a2[s][ns][2]);
                o.w = silu_f(a2[s][ns][3]);
                *(float4*)&xdown[(size_t)mm * 64 + n0] = o;
            }
        }
    }
}

// ====== fused update chain (BM=128, ping-pong LDS) + fused outseg =========
__global__ __launch_bounds__(512, 2) void chain_kernel(
    const float* __restrict__ seg, const float* __restrict__ xji, float* __restrict__ m,
    const unsigned short* __restrict__ uph, const unsigned short* __restrict__ upl,
    const unsigned short* __restrict__ r1h, const unsigned short* __restrict__ r1l,
    const float* __restrict__ r1b,
    const unsigned short* __restrict__ skh, const unsigned short* __restrict__ skl,
    const float* __restrict__ skb,
    const unsigned short* __restrict__ r2h, const unsigned short* __restrict__ r2l,
    const float* __restrict__ r2b,
    const float* __restrict__ rbf6, const float* __restrict__ orw,
    const int* __restrict__ idxi, float* __restrict__ atom1) {
    __shared__ unsigned short XsA[128 * 136];
    __shared__ unsigned short XsB[128 * 136];
    __shared__ float Bs[896];    // r1b(256) skb(128) r2b(512)
    __shared__ float Ow[768];    // orw [6][128]
    __shared__ float Rr[768];    // rbf rows [128][6]
    __shared__ int Ii[128];
    int tid = threadIdx.x, bm = blockIdx.x * 128;
    int wid = tid >> 6, lane = tid & 63;
    int wr = wid >> 2, wc = wid & 3;
    int r16 = lane & 15, kg = lane >> 4;
    int arow0 = wr * 64, bcol0 = wc * 32;

    // preload small tables
    for (int i = tid; i < 896; i += 512)
        Bs[i] = (i < 256) ? r1b[i] : (i < 384) ? skb[i - 256] : r2b[i - 384];
    for (int i = tid; i < 768; i += 512) Ow[i] = orw[i];
    for (int i = tid; i < 768; i += 512) Rr[i] = rbf6[(size_t)bm * 6 + i];
    if (tid < 128) Ii[tid] = idxi[bm + tid];

    // stage seg (128x64 fp32) -> A
    #pragma unroll
    for (int p = 0; p < 4; p++) {
        int idx = tid + p * 512, row = idx >> 4, cg = idx & 15;
        float4 v = *(const float4*)&seg[(size_t)(bm + row) * 64 + cg * 4];
        *(uint2*)&XsA[row * 136 + cg * 4] = pk4(v.x, v.y, v.z, v.w);
    }
    __syncthreads();

    f32x4 acc[4][2], res[4][2];

    auto store_frags = [&](unsigned short* Xd, const f32x4 (&v)[4][2]) {
        #pragma unroll
        for (int s = 0; s < 4; s++)
            #pragma unroll
            for (int ns = 0; ns < 2; ns++)
                *(uint2*)&Xd[(arow0 + s * 16 + r16) * 136 + bcol0 + ns * 16 + kg * 4] =
                    pk4(v[s][ns][0], v[s][ns][1], v[s][ns][2], v[s][ns][3]);
    };
    auto store_act = [&](unsigned short* Xd, const f32x4 (&a)[4][2], const float* bb) {
        #pragma unroll
        for (int s = 0; s < 4; s++)
            #pragma unroll
            for (int ns = 0; ns < 2; ns++) {
                int n0 = bcol0 + ns * 16 + kg * 4;
                float4 b4 = *(const float4*)&bb[n0];
                *(uint2*)&Xd[(arow0 + s * 16 + r16) * 136 + n0] =
                    pk4(silu_f(a[s][ns][0] + b4.x), silu_f(a[s][ns][1] + b4.y),
                        silu_f(a[s][ns][2] + b4.z), silu_f(a[s][ns][3] + b4.w));
            }
    };
    auto accum_res = [&](const f32x4 (&a)[4][2], const float* bb) {
        #pragma unroll
        for (int s = 0; s < 4; s++)
            #pragma unroll
            for (int ns = 0; ns < 2; ns++) {
                int n0 = bcol0 + ns * 16 + kg * 4;
                float4 b4 = *(const float4*)&bb[n0];
                res[s][ns][0] += silu_f(a[s][ns][0] + b4.x);
                res[s][ns][1] += silu_f(a[s][ns][1] + b4.y);
                res[s][ns][2] += silu_f(a[s][ns][2] + b4.z);
                res[s][ns][3] += silu_f(a[s][ns][3] + b4.w);
            }
    };

    // ---- up: read A, res = xji + silu(acc), write B
    mfma_stage_pp<2, 4, 2, 136>(XsA, uph, upl, 64, arow0, bcol0, r16, kg, acc);
    #pragma unroll
    for (int s = 0; s < 4; s++) {
        int mm = bm + arow0 + s * 16 + r16;
        #pragma unroll
        for (int ns = 0; ns < 2; ns++) {
            int n0 = bcol0 + ns * 16 + kg * 4;
            float4 xv = *(const float4*)&xji[(size_t)mm * 128 + n0];
            res[s][ns][0] = silu_f(acc[s][ns][0]) + xv.x;
            res[s][ns][1] = silu_f(acc[s][ns][1]) + xv.y;
            res[s][ns][2] = silu_f(acc[s][ns][2]) + xv.z;
            res[s][ns][3] = silu_f(acc[s][ns][3]) + xv.w;
        }
    }
    store_frags(XsB, res);
    __syncthreads();

    // ---- res1 a
    mfma_stage_pp<4, 4, 2, 136>(XsB, r1h, r1l, 128, arow0, bcol0, r16, kg, acc);
    store_act(XsA, acc, &Bs[0]);
    __syncthreads();
    // ---- res1 b
    mfma_stage_pp<4, 4, 2, 136>(XsA, r1h + 16384, r1l + 16384, 128, arow0, bcol0, r16, kg, acc);
    accum_res(acc, &Bs[128]);
    store_frags(XsB, res);
    __syncthreads();

    // ---- skip + m residual
    mfma_stage_pp<4, 4, 2, 136>(XsB, skh, skl, 128, arow0, bcol0, r16, kg, acc);
    #pragma unroll
    for (int s = 0; s < 4; s++) {
        int mm = bm + arow0 + s * 16 + r16;
        #pragma unroll
        for (int ns = 0; ns < 2; ns++) {
            int n0 = bcol0 + ns * 16 + kg * 4;
            float bsk0 = Bs[256 + n0], bsk1 = Bs[256 + n0 + 1];
            float bsk2 = Bs[256 + n0 + 2], bsk3 = Bs[256 + n0 + 3];
            float4 mv = *(const float4*)&m[(size_t)mm * 128 + n0];
            res[s][ns][0] = silu_f(acc[s][ns][0] + bsk0) + mv.x;
            res[s][ns][1] = silu_f(acc[s][ns][1] + bsk1) + mv.y;
            res[s][ns][2] = silu_f(acc[s][ns][2] + bsk2) + mv.z;
            res[s][ns][3] = silu_f(acc[s][ns][3] + bsk3) + mv.w;
        }
    }
    store_frags(XsA, res);
    __syncthreads();

    // ---- res2[0]
    mfma_stage_pp<4, 4, 2, 136>(XsA, r2h, r2l, 128, arow0, bcol0, r16, kg, acc);
    store_act(XsB, acc, &Bs[384]);
    __syncthreads();
    mfma_stage_pp<4, 4, 2, 136>(XsB, r2h + 16384, r2l + 16384, 128, arow0, bcol0, r16, kg, acc);
    accum_res(acc, &Bs[512]);
    store_frags(XsA, res);
    __syncthreads();
    // ---- res2[1]
    mfma_stage_pp<4, 4, 2, 136>(XsA, r2h + 32768, r2l + 32768, 128, arow0, bcol0, r16, kg, acc);
    store_act(XsB, acc, &Bs[640]);
    __syncthreads();
    mfma_stage_pp<4, 4, 2, 136>(XsB, r2h + 49152, r2l + 49152, 128, arow0, bcol0, r16, kg, acc);
    accum_res(acc, &Bs[768]);

    // write final m + fused outseg atomics
    #pragma unroll
    for (int s = 0; s < 4; s++) {
        int row = arow0 + s * 16 + r16;
        int mm = bm + row;
        float rv[6];
        #pragma unroll
        for (int k = 0; k < 6; k++) rv[k] = Rr[row * 6 + k];
        int ai = Ii[row];
        #pragma unroll
        for (int ns = 0; ns < 2; ns++) {
            int n0 = bcol0 + ns * 16 + kg * 4;
            float4 o;
            o.x = res[s][ns][0]; o.y = res[s][ns][1];
            o.z = res[s][ns][2]; o.w = res[s][ns][3];
            *(float4*)&m[(size_t)mm * 128 + n0] = o;
            #pragma unroll
            for (int j = 0; j < 4; j++) {
                int c = n0 + j;
                float sc = 0.f;
                #pragma unroll
                for (int k = 0; k < 6; k++) sc = fmaf(rv[k], Ow[k * 128 + c], sc);
                atomicAdd(&atom1[(size_t)ai * 128 + c], sc * res[s][ns][j]);
            }
        }
    }
}

// ===================== triplet phase: counting sort by reduce_to_ji =======
__global__ __launch_bounds__(256) void hist_kernel(const int* __restrict__ rji,
                                                   int* __restrict__ hist) {
    int t = blockIdx.x * 256 + threadIdx.x;
    atomicAdd(&hist[rji[t]], 1);
}

__global__ __launch_bounds__(256) void scan1_kernel(const int* __restrict__ hist,
                                                    int* __restrict__ bsum) {
    __shared__ int s[256];
    int i = threadIdx.x;
    s[i] = hist[blockIdx.x * 256 + i];
    __syncthreads();
    for (int o = 128; o; o >>= 1) {
        if (i < o) s[i] += s[i + o];
        __syncthreads();
    }
    if (!i) bsum[blockIdx.x] = s[0];
}

__global__ __launch_bounds__(256) void scan2_kernel(const int* __restrict__ bsum,
                                                    int* __restrict__ boff) {
    __shared__ int s[256];
    int i = threadIdx.x;
    int own = bsum[i];
    s[i] = own;
    __syncthreads();
    for (int o = 1; o < 256; o <<= 1) {
        int v = (i >= o) ? s[i - o] : 0;
        __syncthreads();
        s[i] += v;
        __syncthreads();
    }
    boff[i] = s[i] - own;
}

__global__ __launch_bounds__(256) void scan3_kernel(const int* __restrict__ hist,
                                                    const int* __restrict__ boff,
                                                    int* __restrict__ rows,
                                                    int* __restrict__ cursor, int T) {
    __shared__ int s[256];
    int i = threadIdx.x, b = blockIdx.x;
    int h = hist[b * 256 + i];
    s[i] = h;
    __syncthreads();
    for (int o = 1; o < 256; o <<= 1) {
        int v = (i >= o) ? s[i - o] : 0;
        __syncthreads();
        s[i] += v;
        __syncthreads();
    }
    int excl = s[i] - h + boff[b];
    rows[b * 256 + i] = excl;
    cursor[b * 256 + i] = excl;
    if (b == gridDim.x - 1 && i == 255) rows[b * 256 + 256] = T;
}

__global__ __launch_bounds__(256) void scatter_kernel(
    const int* __restrict__ rji, const int* __restrict__ ekj,
    int* __restrict__ cursor, int* __restrict__ perm, int* __restrict__ ekjs) {
    int t = blockIdx.x * 256 + threadIdx.x;
    int r = rji[t];
    int pos = atomicAdd(&cursor[r], 1);
    perm[pos] = t;
    ekjs[pos] = ekj[t];
}

// ------------- sbf precompute: trig once, contract with all 4 blocks' sbf1
__global__ __launch_bounds__(256) void sbf_pre_kernel(
    const float* __restrict__ dist, const float* __restrict__ angles,
    const int* __restrict__ perm, const int* __restrict__ ekjs,
    const float* __restrict__ sbf1_all, unsigned short* __restrict__ t32, int T) {
    __shared__ float s1[1344];
    int tid = threadIdx.x;
    for (int i = tid; i < 1344; i += 256) s1[i] = sbf1_all[i];
    __syncthreads();

    int pos = blockIdx.x * 256 + tid;
    int t = perm[pos];
    int e = ekjs[pos];
    float x = fmaxf(dist[e] * 0.2f, 1e-6f);
    float env = 0.f;
    if (x < 1.0f) {
        float x2 = x * x;
        float x5 = x2 * x2 * x;
        env = 1.0f / x + x5 * (-28.0f + x * (48.0f - 21.0f * x));
    }
    float ct = __cosf(angles[t]);
    float Pl[7];
    Pl[0] = 1.f;
    Pl[1] = ct;
    #pragma unroll
    for (int l = 2; l < 7; l++)
        Pl[l] = ((2.f * l - 1.f) * ct * Pl[l - 1] - (l - 1.f) * Pl[l - 2]) / (float)l;
    const float sphc[7] = {0.28209479f, 0.48860251f, 0.63078313f, 0.74635267f,
                           0.84628438f, 0.93560257f, 1.01710723f};
    const float BZ[7][6] = {
        {3.141593f, 6.283185f, 9.424778f, 12.566371f, 15.707963f, 18.849556f},
        {4.493409f, 7.725252f, 10.904122f, 14.066194f, 17.220755f, 20.371303f},
        {5.763459f, 9.095011f, 12.322941f, 15.514603f, 18.689036f, 21.853874f},
        {6.987932f, 10.417119f, 13.698023f, 16.923621f, 20.121806f, 23.304247f},
        {8.182561f, 11.704907f, 15.039665f, 18.301256f, 21.525418f, 24.727566f},
        {9.355812f, 12.966530f, 16.354710f, 19.653152f, 22.904551f, 26.126750f},
        {10.512835f, 14.207392f, 17.647975f, 20.983463f, 24.262768f, 27.507868f}};
    float sbf[42];
    #pragma unroll
    for (int l = 0; l < 7; l++) {
        float coef = env * sphc[l] * Pl[l];
        #pragma unroll
        for (int n = 0; n < 6; n++) {
            float a = BZ[l][n] * x;
            float sa, ca;
            __sincosf(a, &sa, &ca);
            float inv = __builtin_amdgcn_rcpf(a);
            float j;
            if (l == 0) {
                j = sa * inv;
            } else {
                float jm2 = sa * inv;
                float jm1 = (sa * inv - ca) * inv;
                #pragma unroll
                for (int ll = 2; ll <= l; ll++) {
                    float jn = (2.f * ll - 1.f) * inv * jm1 - jm2;
                    jm2 = jm1;
                    jm1 = jn;
                }
                j = jm1;
            }
            sbf[l * 6 + n] = coef * j;
        }
    }
    float acc[32];
    #pragma unroll
    for (int q = 0; q < 32; q++) acc[q] = 0.f;
    #pragma unroll
    for (int k = 0; k < 42; k++) {
        float sv = sbf[k];
        #pragma unroll
        for (int b = 0; b < 4; b++)
            #pragma unroll
            for (int p = 0; p < 8; p++)
                acc[b * 8 + p] = fmaf(sv, s1[b * 336 + k * 8 + p], acc[b * 8 + p]);
    }
    #pragma unroll
    for (int b = 0; b < 4; b++) {
        uint4 u;
        u.x = packbf2(acc[b * 8 + 0], acc[b * 8 + 1]);
        u.y = packbf2(acc[b * 8 + 2], acc[b * 8 + 3]);
        u.z = packbf2(acc[b * 8 + 4], acc[b * 8 + 5]);
        u.w = packbf2(acc[b * 8 + 6], acc[b * 8 + 7]);
        *(uint4*)&t32[((size_t)b * T + pos) * 8] = u;
    }
}

// ------------- per-block gather reduce: one wave per target edge, no atomics
__global__ __launch_bounds__(256) void seg_gather_kernel(
    const unsigned short* __restrict__ t32p, const int* __restrict__ ekjs,
    const int* __restrict__ rows, const float* __restrict__ xdown,
    const float* __restrict__ sbf2, float* __restrict__ seg, int E) {
    int gid = blockIdx.x * 256 + threadIdx.x;
    int e = gid >> 6, lane = gid & 63;
    if (e >= E) return;
    float w2[8];
    #pragma unroll
    for (int p = 0; p < 8; p++) w2[p] = sbf2[p * 64 + lane];
    int p0 = rows[e], p1 = rows[e + 1];
    float acc = 0.f;
    for (int pos = p0; pos < p1; ++pos) {
        uint4 a = *(const uint4*)&t32p[(size_t)pos * 8];
        float v = __uint_as_float(a.x << 16) * w2[0] + __uint_as_float(a.x & 0xffff0000u) * w2[1]
                + __uint_as_float(a.y << 16) * w2[2] + __uint_as_float(a.y & 0xffff0000u) * w2[3]
                + __uint_as_float(a.z << 16) * w2[4] + __uint_as_float(a.z & 0xffff0000u) * w2[5]
                + __uint_as_float(a.w << 16) * w2[6] + __uint_as_float(a.w & 0xffff0000u) * w2[7];
        acc = fmaf(v, xdown[(size_t)ekjs[pos] * 64 + lane], acc);
    }
    seg[(size_t)e * 64 + lane] = acc;
}

// ---------------------------------------------------------------- launcher
extern "C" void kernel_launch(void* const* d_in, const int* in_sizes, int n_in,
                              void* d_out, int out_size, void* d_ws, size_t ws_size,
                              hipStream_t stream) {
    const float* distances   = (const float*)d_in[0];
    const float* angles      = (const float*)d_in[1];
    const float* species_emb = (const float*)d_in[2];
    const float* emb_rbf_w   = (const float*)d_in[3];
    const float* emb_rbf_b   = (const float*)d_in[4];
    const float* emb_dense_w = (const float*)d_in[5];
    const float* emb_dense_b = (const float*)d_in[6];
    const float* out_rbf_w   = (const float*)d_in[7];
    const float* out_up_w    = (const float*)d_in[8];
    const float* out_dense_w = (const float*)d_in[9];
    const float* out_dense_b = (const float*)d_in[10];
    const float* out_final_w = (const float*)d_in[11];
    const float* int_ji_w    = (const float*)d_in[12];
    const float* int_ji_b    = (const float*)d_in[13];
    const float* int_kj_w    = (const float*)d_in[14];
    const float* int_kj_b    = (const float*)d_in[15];
    const float* int_rbf1_w  = (const float*)d_in[16];
    const float* int_rbf2_w  = (const float*)d_in[17];
    const float* int_down_w  = (const float*)d_in[18];
    const float* int_sbf1_w  = (const float*)d_in[19];
    const float* int_sbf2_w  = (const float*)d_in[20];
    const float* int_up_w    = (const float*)d_in[21];
    const float* int_res1_w  = (const float*)d_in[22];
    const float* int_res1_b  = (const float*)d_in[23];
    const float* int_skip_w  = (const float*)d_in[24];
    const float* int_skip_b  = (const float*)d_in[25];
    const float* int_res2_w  = (const float*)d_in[26];
    const float* int_res2_b  = (const float*)d_in[27];
    const int*   species     = (const int*)d_in[28];
    const int*   idx_i       = (const int*)d_in[29];
    const int*   idx_j       = (const int*)d_in[30];
    const int*   reduce_ji   = (const int*)d_in[31];
    const int*   expand_kj   = (const int*)d_in[32];

    const int E = in_sizes[0];       // 65536
    const int T = in_sizes[1];       // 524288
    const int NA = in_sizes[28];     // 4096

    float* ws = (float*)d_ws;
    size_t off = 0;
    float* rbf = ws + off;   off += (size_t)E * 6;
    float* m   = ws + off;   off += (size_t)E * 128;
    float* A   = ws + off;   off += (size_t)E * 128;   // x_ji
    float* B   = ws + off;   off += (size_t)E * 128;   // seg (E x 64 used)
    float* C   = ws + off;   off += (size_t)E * 128;   // spare
    float* D   = ws + off;   off += (size_t)E * 64;    // xdown
    float* HWj = ws + off;   off += 16 * 128;
    float* HWi = ws + off;   off += 16 * 128;
    float* W3  = ws + off;   off += 6 * 128;
    float* b3  = ws + off;   off += 128;
    float* atom1 = ws + off; off += (size_t)NA * 128;
    float* atom2 = ws + off; off += (size_t)NA * 256;
    float* atom3 = ws + off; off += (size_t)NA * 256;
    float* seg = B;

    unsigned short* wb = (unsigned short*)(ws + off);
    size_t wo = 0;
    unsigned short* ji_h = wb + wo;  wo += 4 * 16384;
    unsigned short* ji_l = wb + wo;  wo += 4 * 16384;
    unsigned short* kj_h = wb + wo;  wo += 4 * 16384;
    unsigned short* kj_l = wb + wo;  wo += 4 * 16384;
    unsigned short* dn_h = wb + wo;  wo += 4 * 8192;
    unsigned short* dn_l = wb + wo;  wo += 4 * 8192;
    unsigned short* up_h = wb + wo;  wo += 4 * 8192;
    unsigned short* up_l = wb + wo;  wo += 4 * 8192;
    unsigned short* r1_h = wb + wo;  wo += 8 * 16384;
    unsigned short* r1_l = wb + wo;  wo += 8 * 16384;
    unsigned short* sk_h = wb + wo;  wo += 4 * 16384;
    unsigned short* sk_l = wb + wo;  wo += 4 * 16384;
    unsigned short* r2_h = wb + wo;  wo += 16 * 16384;
    unsigned short* r2_l = wb + wo;  wo += 16 * 16384;
    unsigned short* ou_h = wb + wo;  wo += 5 * 32768;
    unsigned short* ou_l = wb + wo;  wo += 5 * 32768;
    unsigned short* od_h = wb + wo;  wo += 15 * 65536;
    unsigned short* od_l = wb + wo;  wo += 15 * 65536;
    unsigned short* t32 = wb + wo;   wo += (size_t)4 * T * 8;
    int* ip    = (int*)(wb + wo);
    size_t io  = 0;
    int* hist   = ip + io;  io += E;
    int* rows   = ip + io;  io += E + 64;
    int* cursor = ip + io;  io += E;
    int* bsum   = ip + io;  io += 256;
    int* boff   = ip + io;  io += 256;
    int* perm   = ip + io;  io += T;
    int* ekjs   = ip + io;  io += T;

    float* out = (float*)d_out;
    hipMemsetAsync(out, 0, (size_t)out_size * sizeof(float), stream);

    // ---- triplet counting sort + basis precompute (once per launch)
    hipMemsetAsync(hist, 0, (size_t)E * sizeof(int), stream);
    hist_kernel<<<T / 256, 256, 0, stream>>>(reduce_ji, hist);
    scan1_kernel<<<E / 256, 256, 0, stream>>>(hist, bsum);
    scan2_kernel<<<1, 256, 0, stream>>>(bsum, boff);
    scan3_kernel<<<E / 256, 256, 0, stream>>>(hist, boff, rows, cursor, T);
    scatter_kernel<<<T / 256, 256, 0, stream>>>(reduce_ji, expand_kj, cursor, perm, ekjs);
    sbf_pre_kernel<<<T / 256, 256, 0, stream>>>(distances, angles, perm, ekjs,
                                                int_sbf1_w, t32, T);

    // weight conversion (once per launch)
    wconv_kernel<<<dim3(4, 4, 4), 256, 0, stream>>>(int_ji_w, ji_h, ji_l, 128, 128);
    wconv_kernel<<<dim3(4, 4, 4), 256, 0, stream>>>(int_kj_w, kj_h, kj_l, 128, 128);
    wconv_kernel<<<dim3(2, 4, 4), 256, 0, stream>>>(int_down_w, dn_h, dn_l, 128, 64);
    wconv_kernel<<<dim3(4, 2, 4), 256, 0, stream>>>(int_up_w, up_h, up_l, 64, 128);
    wconv_kernel<<<dim3(4, 4, 8), 256, 0, stream>>>(int_res1_w, r1_h, r1_l, 128, 128);
    wconv_kernel<<<dim3(4, 4, 4), 256, 0, stream>>>(int_skip_w, sk_h, sk_l, 128, 128);
    wconv_kernel<<<dim3(4, 4, 16), 256, 0, stream>>>(int_res2_w, r2_h, r2_l, 128, 128);
    wconv_kernel<<<dim3(8, 4, 5), 256, 0, stream>>>(out_up_w, ou_h, ou_l, 128, 256);
    wconv_kernel<<<dim3(8, 8, 15), 256, 0, stream>>>(out_dense_w, od_h, od_l, 256, 256);

    rbf_kernel<<<E / 256, 256, 0, stream>>>(distances, rbf, E);
    embed_pre_kernel<<<1, 128, 0, stream>>>(species_emb, emb_rbf_w, emb_rbf_b,
                                            emb_dense_w, HWj, HWi, W3, b3);
    // block-0 outseg fused into embed
    hipMemsetAsync(atom1, 0, (size_t)NA * 128 * sizeof(float), stream);
    embed_kernel<<<E * 128 / 256, 256, 0, stream>>>(rbf, species, idx_i, idx_j,
                                                    HWj, HWi, W3, b3, emb_dense_b,
                                                    out_rbf_w, m, atom1);

    auto outtail = [&](int i) {
        mfma_gemmT<0, 0, 0><<<dim3(NA / 64, 2), 512, 0, stream>>>(
            atom1, ou_h + (size_t)i * 32768, ou_l + (size_t)i * 32768,
            nullptr, nullptr, atom2, NA, 128, 256);
        outchain_kernel<<<NA / 64, 512, 0, stream>>>(
            atom2, od_h + (size_t)i * 3 * 65536, od_l + (size_t)i * 3 * 65536,
            out_dense_b + (size_t)i * 3 * 256, out_final_w + (size_t)i * 256, out);
    };

    outtail(0);

    for (int i = 0; i < 4; i++) {
        downpath_kernel<<<E / 128, 512, 0, stream>>>(
            m, rbf, int_rbf1_w + (size_t)i * 48, int_rbf2_w + (size_t)i * 1024,
            ji_h + (size_t)i * 16384, ji_l + (size_t)i * 16384, int_ji_b + (size_t)i * 128,
            kj_h + (size_t)i * 16384, kj_l + (size_t)i * 16384, int_kj_b + (size_t)i * 128,
            dn_h + (size_t)i * 8192, dn_l + (size_t)i * 8192,
            A, D);
        seg_gather_kernel<<<E * 64 / 256, 256, 0, stream>>>(
            t32 + (size_t)i * T * 8, ekjs, rows, D,
            int_sbf2_w + (size_t)i * 8 * 64, seg, E);
        hipMemsetAsync(atom1, 0, (size_t)NA * 128 * sizeof(float), stream);
        chain_kernel<<<E / 128, 512, 0, stream>>>(
            seg, A, m,
            up_h + (size_t)i * 8192, up_l + (size_t)i * 8192,
            r1_h + (size_t)i * 32768, r1_l + (size_t)i * 32768, int_res1_b + (size_t)i * 256,
            sk_h + (size_t)i * 16384, sk_l + (size_t)i * 16384, int_skip_b + (size_t)i * 128,
            r2_h + (size_t)i * 65536, r2_l + (size_t)i * 65536, int_res2_b + (size_t)i * 512,
            rbf, out_rbf_w + (size_t)(i + 1) * 768, idx_i, atom1);
        outtail(i + 1);
    }
}

// Round 12
// 1465.496 us; speedup vs baseline: 1.2120x; 1.2120x over previous
//
#include <hip/hip_runtime.h>
#include <cmath>

typedef __attribute__((ext_vector_type(8))) short bfrag;   // 8 bf16 = 4 VGPRs
typedef __attribute__((ext_vector_type(4))) float f32x4;

// ---------------------------------------------------------------- helpers
__device__ __forceinline__ float silu_f(float x) {
    return x * __builtin_amdgcn_rcpf(1.0f + __expf(-x));
}
__device__ __forceinline__ unsigned short f2bf(float f) {
    unsigned u = __float_as_uint(f);
    unsigned r = (u + 0x7fff + ((u >> 16) & 1)) >> 16;
    return (unsigned short)r;
}
__device__ __forceinline__ float bf2f(unsigned short h) {
    return __uint_as_float(((unsigned)h) << 16);
}
__device__ __forceinline__ unsigned packbf2(float lo, float hi) {
    return ((unsigned)f2bf(hi) << 16) | (unsigned)f2bf(lo);
}
__device__ __forceinline__ unsigned cvtpk2(float a, float b) {
    unsigned r;
    asm("v_cvt_pk_bf16_f32 %0, %1, %2" : "=v"(r) : "v"(a), "v"(b));
    return r;
}
__device__ __forceinline__ uint2 pk4(float a, float b, float c, float d) {
    return make_uint2(cvtpk2(a, b), cvtpk2(c, d));
}

// plain stage (outchain/gemmT)
template <int KSTEPS, int S, int NS, int ST>
__device__ __forceinline__ void mfma_stage_T(
    const unsigned short* Xs,
    const unsigned short* __restrict__ Whi, const unsigned short* __restrict__ Wlo,
    int Kdim, int arow0, int bcol0, int r16, int kg, f32x4 (&acc)[S][NS]) {
    #pragma unroll
    for (int s = 0; s < S; s++)
        #pragma unroll
        for (int ns = 0; ns < NS; ns++) acc[s][ns] = (f32x4)0.f;
    #pragma unroll
    for (int ks = 0; ks < KSTEPS; ks++) {
        int k0 = ks * 32;
        bfrag wh[NS], wl[NS];
        #pragma unroll
        for (int ns = 0; ns < NS; ns++) {
            size_t o = (size_t)(bcol0 + ns * 16 + r16) * Kdim + k0 + kg * 8;
            wh[ns] = *(const bfrag*)&Whi[o];
            wl[ns] = *(const bfrag*)&Wlo[o];
        }
        #pragma unroll
        for (int s = 0; s < S; s++) {
            bfrag xh = *(const bfrag*)&Xs[(arow0 + s * 16 + r16) * ST + k0 + kg * 8];
            #pragma unroll
            for (int ns = 0; ns < NS; ns++) {
                acc[s][ns] = __builtin_amdgcn_mfma_f32_16x16x32_bf16(wh[ns], xh, acc[s][ns], 0, 0, 0);
                acc[s][ns] = __builtin_amdgcn_mfma_f32_16x16x32_bf16(wl[ns], xh, acc[s][ns], 0, 0, 0);
            }
        }
    }
}

// pipelined stage (chain/downpath): W frags for ks+1 issued before ks's MFMAs
template <int KSTEPS, int S, int NS, int ST>
__device__ __forceinline__ void mfma_stage_pp(
    const unsigned short* Xs,
    const unsigned short* __restrict__ Whi, const unsigned short* __restrict__ Wlo,
    int Kdim, int arow0, int bcol0, int r16, int kg, f32x4 (&acc)[S][NS]) {
    bfrag wh[2][NS], wl[2][NS];
    #pragma unroll
    for (int ns = 0; ns < NS; ns++) {
        size_t o = (size_t)(bcol0 + ns * 16 + r16) * Kdim + kg * 8;
        wh[0][ns] = *(const bfrag*)&Whi[o];
        wl[0][ns] = *(const bfrag*)&Wlo[o];
    }
    #pragma unroll
    for (int s = 0; s < S; s++)
        #pragma unroll
        for (int ns = 0; ns < NS; ns++) acc[s][ns] = (f32x4)0.f;
    #pragma unroll
    for (int ks = 0; ks < KSTEPS; ks++) {
        const int cur = ks & 1, nxt = cur ^ 1;
        if (ks + 1 < KSTEPS) {
            #pragma unroll
            for (int ns = 0; ns < NS; ns++) {
                size_t o = (size_t)(bcol0 + ns * 16 + r16) * Kdim + (ks + 1) * 32 + kg * 8;
                wh[nxt][ns] = *(const bfrag*)&Whi[o];
                wl[nxt][ns] = *(const bfrag*)&Wlo[o];
            }
        }
        #pragma unroll
        for (int s = 0; s < S; s++) {
            bfrag xh = *(const bfrag*)&Xs[(arow0 + s * 16 + r16) * ST + ks * 32 + kg * 8];
            #pragma unroll
            for (int ns = 0; ns < NS; ns++) {
                acc[s][ns] = __builtin_amdgcn_mfma_f32_16x16x32_bf16(wh[cur][ns], xh, acc[s][ns], 0, 0, 0);
                acc[s][ns] = __builtin_amdgcn_mfma_f32_16x16x32_bf16(wl[cur][ns], xh, acc[s][ns], 0, 0, 0);
            }
        }
    }
}

// ---------------------------------------------------------------- rbf (E,6)
__global__ __launch_bounds__(256) void rbf_kernel(const float* __restrict__ d,
                                                  float* __restrict__ rbf, int E) {
    int e = blockIdx.x * 256 + threadIdx.x;
    if (e >= E) return;
    float x = d[e] * 0.2f;
    float env = 0.0f;
    if (x < 1.0f) {
        float x2 = x * x;
        float x5 = x2 * x2 * x;
        env = 1.0f / x + x5 * (-28.0f + x * (48.0f - 21.0f * x));
    }
    const float SQ = 0.63245553f;
    float px = 3.14159265358979f * x;
    #pragma unroll
    for (int n = 1; n <= 6; n++) {
        rbf[e * 6 + n - 1] = SQ * env * __sinf(px * (float)n);
    }
}

// ------------------------------------------- embedding precompute (1 block)
__global__ __launch_bounds__(128) void embed_pre_kernel(
    const float* __restrict__ se, const float* __restrict__ erw,
    const float* __restrict__ erb, const float* __restrict__ edw,
    float* __restrict__ HWj, float* __restrict__ HWi,
    float* __restrict__ W3, float* __restrict__ b3) {
    int c = threadIdx.x;
    for (int s = 0; s < 16; s++) {
        float aj = 0.f, ai = 0.f;
        for (int k = 0; k < 64; k++) {
            float h = se[s * 64 + k];
            aj += h * edw[k * 128 + c];
            ai += h * edw[(64 + k) * 128 + c];
        }
        HWj[s * 128 + c] = aj;
        HWi[s * 128 + c] = ai;
    }
    for (int r = 0; r < 6; r++) {
        float a = 0.f;
        for (int k = 0; k < 128; k++) a += erw[r * 128 + k] * edw[(128 + k) * 128 + c];
        W3[r * 128 + c] = a;
    }
    float a = 0.f;
    for (int k = 0; k < 128; k++) a += erb[k] * edw[(128 + k) * 128 + c];
    b3[c] = a;
}

// --------------- m (E,128) + fused outseg for output block 0 (coalesced)
__global__ __launch_bounds__(256) void embed_kernel(
    const float* __restrict__ rbf, const int* __restrict__ species,
    const int* __restrict__ idx_i, const int* __restrict__ idx_j,
    const float* __restrict__ HWj, const float* __restrict__ HWi,
    const float* __restrict__ W3, const float* __restrict__ b3,
    const float* __restrict__ edb, const float* __restrict__ orw0,
    float* __restrict__ m, float* __restrict__ atom1) {
    int gid = blockIdx.x * 256 + threadIdx.x;
    int e = gid >> 7, c = gid & 127;
    int sj = species[idx_j[e]];
    int si = species[idx_i[e]];
    float rv[6];
    #pragma unroll
    for (int k = 0; k < 6; k++) rv[k] = rbf[e * 6 + k];
    float v = HWj[sj * 128 + c] + HWi[si * 128 + c] + b3[c] + edb[c];
    #pragma unroll
    for (int k = 0; k < 6; k++) v += rv[k] * W3[k * 128 + c];
    v = silu_f(v);
    m[gid] = v;
    float sc = 0.f;
    #pragma unroll
    for (int k = 0; k < 6; k++) sc += rv[k] * orw0[k * 128 + c];
    atomicAdd(&atom1[(size_t)idx_i[e] * 128 + c], sc * v);
}

// -------------------------------------- weight transpose+split (batched)
__global__ __launch_bounds__(256) void wconv_kernel(
    const float* __restrict__ W, unsigned short* __restrict__ hi,
    unsigned short* __restrict__ lo, int K, int N) {
    __shared__ float t[32][33];
    int b = blockIdx.z;
    int n0 = blockIdx.x * 32, k0 = blockIdx.y * 32;
    const float* Wb = W + (size_t)b * K * N;
    int tid = threadIdx.x;
    int r = tid >> 3, cg = tid & 7;
    float4 v = *(const float4*)&Wb[(size_t)(k0 + r) * N + n0 + cg * 4];
    t[r][cg * 4 + 0] = v.x;
    t[r][cg * 4 + 1] = v.y;
    t[r][cg * 4 + 2] = v.z;
    t[r][cg * 4 + 3] = v.w;
    __syncthreads();
    int nl = tid >> 3, kg = tid & 7;
    short4 h4, l4;
    float f0 = t[kg * 4 + 0][nl], f1 = t[kg * 4 + 1][nl];
    float f2 = t[kg * 4 + 2][nl], f3 = t[kg * 4 + 3][nl];
    unsigned short h;
    h = f2bf(f0); h4.x = (short)h; l4.x = (short)f2bf(f0 - bf2f(h));
    h = f2bf(f1); h4.y = (short)h; l4.y = (short)f2bf(f1 - bf2f(h));
    h = f2bf(f2); h4.z = (short)h; l4.z = (short)f2bf(f2 - bf2f(h));
    h = f2bf(f3); h4.w = (short)h; l4.w = (short)f2bf(f3 - bf2f(h));
    size_t o = ((size_t)b * N + n0 + nl) * K + k0 + kg * 4;
    *(short4*)&hi[o] = h4;
    *(short4*)&lo[o] = l4;
}

// --------------------- transposed-output dense GEMM, BM=64 tile
template <int ACT, int BIAS, int RES>
__global__ __launch_bounds__(512, 4) void mfma_gemmT(
    const float* __restrict__ X, const unsigned short* __restrict__ Whi,
    const unsigned short* __restrict__ Wlo,
    const float* __restrict__ bias, const float* __restrict__ resid,
    float* __restrict__ Y, int M, int K, int N) {
    __shared__ unsigned short Xs[64 * 40];
    int tid = threadIdx.x;
    int bm = blockIdx.x * 64, bn = blockIdx.y * 128;
    int wid = tid >> 6, lane = tid & 63;
    int wr = wid >> 2, wc = wid & 3;
    int r16 = lane & 15, kg = lane >> 4;
    int arow0 = wr * 32, bcol0 = wc * 32;

    f32x4 acc[2][2];
    #pragma unroll
    for (int s = 0; s < 2; s++)
        #pragma unroll
        for (int ns = 0; ns < 2; ns++) acc[s][ns] = (f32x4)0.f;

    for (int k0 = 0; k0 < K; k0 += 32) {
        {
            int row = tid >> 3, cg = tid & 7;
            float4 v = *(const float4*)&X[(size_t)(bm + row) * K + k0 + cg * 4];
            *(uint2*)&Xs[row * 40 + cg * 4] = pk4(v.x, v.y, v.z, v.w);
        }
        __syncthreads();
        bfrag wh[2], wl[2];
        #pragma unroll
        for (int ns = 0; ns < 2; ns++) {
            size_t o = (size_t)(bn + bcol0 + ns * 16 + r16) * K + k0 + kg * 8;
            wh[ns] = *(const bfrag*)&Whi[o];
            wl[ns] = *(const bfrag*)&Wlo[o];
        }
        #pragma unroll
        for (int s = 0; s < 2; s++) {
            bfrag xh = *(const bfrag*)&Xs[(arow0 + s * 16 + r16) * 40 + kg * 8];
            #pragma unroll
            for (int ns = 0; ns < 2; ns++) {
                acc[s][ns] = __builtin_amdgcn_mfma_f32_16x16x32_bf16(wh[ns], xh, acc[s][ns], 0, 0, 0);
                acc[s][ns] = __builtin_amdgcn_mfma_f32_16x16x32_bf16(wl[ns], xh, acc[s][ns], 0, 0, 0);
            }
        }
        __syncthreads();
    }
    #pragma unroll
    for (int s = 0; s < 2; s++) {
        int mm = bm + arow0 + s * 16 + r16;
        #pragma unroll
        for (int ns = 0; ns < 2; ns++) {
            int n0 = bn + bcol0 + ns * 16 + kg * 4;
            float bv[4] = {0.f, 0.f, 0.f, 0.f};
            if (BIAS) {
                float4 b4 = *(const float4*)&bias[n0];
                bv[0] = b4.x; bv[1] = b4.y; bv[2] = b4.z; bv[3] = b4.w;
            }
            float4 o;
            float* op = (float*)&o;
            #pragma unroll
            for (int r = 0; r < 4; r++) {
                float v = acc[s][ns][r] + bv[r];
                if (ACT) v = silu_f(v);
                op[r] = v;
            }
            if (RES) {
                float4 rv = *(const float4*)&resid[(size_t)mm * N + n0];
                o.x += rv.x; o.y += rv.y; o.z += rv.z; o.w += rv.w;
            }
            *(float4*)&Y[(size_t)mm * N + n0] = o;
        }
    }
}

// ---------- fused out-block tail: 3x dense(256,silu) + dot(final_w) ------
__global__ __launch_bounds__(512, 4) void outchain_kernel(
    const float* __restrict__ atom2,
    const unsigned short* __restrict__ odh, const unsigned short* __restrict__ odl,
    const float* __restrict__ odb, const float* __restrict__ wf,
    float* __restrict__ out) {
    __shared__ unsigned short Xs[64 * 264];
    __shared__ float rsum[64];
    int tid = threadIdx.x, bm = blockIdx.x * 64;
    int wid = tid >> 6, lane = tid & 63;
    int wr = wid >> 2, wc = wid & 3;
    int r16 = lane & 15, kg = lane >> 4;
    int arow0 = wr * 32, bcol0 = wc * 64;
    if (tid < 64) rsum[tid] = 0.f;

    #pragma unroll
    for (int p = 0; p < 8; p++) {
        int idx = tid + p * 512, row = idx >> 6, cg = idx & 63;
        float4 v = *(const float4*)&atom2[(size_t)(bm + row) * 256 + cg * 4];
        *(uint2*)&Xs[row * 264 + cg * 4] = pk4(v.x, v.y, v.z, v.w);
    }
    __syncthreads();

    f32x4 acc[2][4];
    #pragma unroll
    for (int st = 0; st < 3; st++) {
        mfma_stage_T<8, 2, 4, 264>(Xs, odh + (size_t)st * 65536, odl + (size_t)st * 65536,
                                   256, arow0, bcol0, r16, kg, acc);
        const float* bb = odb + st * 256;
        __syncthreads();
        if (st < 2) {
            #pragma unroll
            for (int s = 0; s < 2; s++)
                #pragma unroll
                for (int ns = 0; ns < 4; ns++) {
                    int n0 = bcol0 + ns * 16 + kg * 4;
                    float4 b4 = *(const float4*)&bb[n0];
                    *(uint2*)&Xs[(arow0 + s * 16 + r16) * 264 + n0] =
                        pk4(silu_f(acc[s][ns][0] + b4.x), silu_f(acc[s][ns][1] + b4.y),
                            silu_f(acc[s][ns][2] + b4.z), silu_f(acc[s][ns][3] + b4.w));
                }
            __syncthreads();
        } else {
            #pragma unroll
            for (int s = 0; s < 2; s++) {
                float part = 0.f;
                #pragma unroll
                for (int ns = 0; ns < 4; ns++) {
                    int n0 = bcol0 + ns * 16 + kg * 4;
                    float4 b4 = *(const float4*)&bb[n0];
                    float4 w4 = *(const float4*)&wf[n0];
                    part += silu_f(acc[s][ns][0] + b4.x) * w4.x;
                    part += silu_f(acc[s][ns][1] + b4.y) * w4.y;
                    part += silu_f(acc[s][ns][2] + b4.z) * w4.z;
                    part += silu_f(acc[s][ns][3] + b4.w) * w4.w;
                }
                atomicAdd(&rsum[arow0 + s * 16 + r16], part);
            }
        }
    }
    __syncthreads();
    if (tid < 64) out[bm + tid] += rsum[tid];
}

// =================== fused down path (BM=128): x_ji, gated x_kj, xdown ====
__global__ __launch_bounds__(512, 4) void downpath_kernel(
    const float* __restrict__ m, const float* __restrict__ rbf,
    const float* __restrict__ rbf1, const float* __restrict__ rbf2,
    const unsigned short* __restrict__ jih, const unsigned short* __restrict__ jil,
    const float* __restrict__ jib,
    const unsigned short* __restrict__ kjh, const unsigned short* __restrict__ kjl,
    const float* __restrict__ kjb,
    const unsigned short* __restrict__ dnh, const unsigned short* __restrict__ dnl,
    float* __restrict__ xji, float* __restrict__ xdown) {
    __shared__ unsigned short XsA[128 * 136];
    __shared__ unsigned short XsB[128 * 136];
    __shared__ float G8t[8][128];
    __shared__ float Rs[8][128];
    int tid = threadIdx.x, bm = blockIdx.x * 128;
    int wid = tid >> 6, lane = tid & 63;
    int wr = wid >> 2, wc = wid & 3;
    int r16 = lane & 15, kg = lane >> 4;
    int arow0 = wr * 64, bcol0 = wc * 32;

    #pragma unroll
    for (int p = 0; p < 8; p++) {
        int idx = tid + p * 512, row = idx >> 5, cg = idx & 31;
        float4 v = *(const float4*)&m[(size_t)(bm + row) * 128 + cg * 4];
        *(uint2*)&XsA[row * 136 + cg * 4] = pk4(v.x, v.y, v.z, v.w);
    }
    if (tid < 128) {
        float rv[6];
        #pragma unroll
        for (int k = 0; k < 6; k++) rv[k] = rbf[(size_t)(bm + tid) * 6 + k];
        #pragma unroll
        for (int p = 0; p < 8; p++) {
            float a = 0.f;
            #pragma unroll
            for (int k = 0; k < 6; k++) a += rv[k] * rbf1[k * 8 + p];
            G8t[p][tid] = a;
        }
    }
    for (int i = tid; i < 1024; i += 512) Rs[i >> 7][i & 127] = rbf2[i];
    __syncthreads();

    f32x4 acc[4][2];
    // ---- x_ji
    mfma_stage_pp<4, 4, 2, 136>(XsA, jih, jil, 128, arow0, bcol0, r16, kg, acc);
    #pragma unroll
    for (int s = 0; s < 4; s++) {
        int mm = bm + arow0 + s * 16 + r16;
        #pragma unroll
        for (int ns = 0; ns < 2; ns++) {
            int n0 = bcol0 + ns * 16 + kg * 4;
            float4 b4 = *(const float4*)&jib[n0];
            float4 o;
            o.x = silu_f(acc[s][ns][0] + b4.x);
            o.y = silu_f(acc[s][ns][1] + b4.y);
            o.z = silu_f(acc[s][ns][2] + b4.z);
            o.w = silu_f(acc[s][ns][3] + b4.w);
            *(float4*)&xji[(size_t)mm * 128 + n0] = o;
        }
    }
    // ---- x_kj gated -> B
    mfma_stage_pp<4, 4, 2, 136>(XsA, kjh, kjl, 128, arow0, bcol0, r16, kg, acc);
    #pragma unroll
    for (int s = 0; s < 4; s++) {
        int mrow = arow0 + s * 16 + r16;
        float g8v[8];
        #pragma unroll
        for (int p = 0; p < 8; p++) g8v[p] = G8t[p][mrow];
        #pragma unroll
        for (int ns = 0; ns < 2; ns++) {
            int n0 = bcol0 + ns * 16 + kg * 4;
            float4 b4 = *(const float4*)&kjb[n0];
            float bb[4] = {b4.x, b4.y, b4.z, b4.w};
            float v[4];
            #pragma unroll
            for (int r = 0; r < 4; r++) {
                float g = 0.f;
                #pragma unroll
                for (int p = 0; p < 8; p++) g = fmaf(g8v[p], Rs[p][n0 + r], g);
                v[r] = silu_f(acc[s][ns][r] + bb[r]) * g;
            }
            *(uint2*)&XsB[mrow * 136 + n0] = pk4(v[0], v[1], v[2], v[3]);
        }
    }
    __syncthreads();
    // ---- xdown (N=64)
    {
        int wr2 = wid >> 1, wc2 = wid & 1;
        int ar2 = wr2 * 32, bc2 = wc2 * 32;
        f32x4 a2[2][2];
        mfma_stage_pp<4, 2, 2, 136>(XsB, dnh, dnl, 128, ar2, bc2, r16, kg, a2);
        #pragma unroll
        for (int s = 0; s < 2; s++) {
            int mm = bm + ar2 + s * 16 + r16;
            #pragma unroll
            for (int ns = 0; ns < 2; ns++) {
                int n0 = bc2 + ns * 16 + kg * 4;
                float4 o;
                o.x = silu_f(a2[s][ns][0]);
                o.y = silu_f(a2[s][ns][1]);
                o.z = silu_f(a2[s][ns][2]);
                o.w = silu_f(a2[s][ns][3]);
                *(float4*)&xdown[(size_t)mm * 64 + n0] = o;
            }
        }
    }
}

// ====== fused update chain (BM=128, ping-pong LDS): up+res1+skip+res2x2 ===
__global__ __launch_bounds__(512, 2) void chain_kernel(
    const float* __restrict__ seg, const float* __restrict__ xji, float* __restrict__ m,
    const unsigned short* __restrict__ uph, const unsigned short* __restrict__ upl,
    const unsigned short* __restrict__ r1h, const unsigned short* __restrict__ r1l,
    const float* __restrict__ r1b,
    const unsigned short* __restrict__ skh, const unsigned short* __restrict__ skl,
    const float* __restrict__ skb,
    const unsigned short* __restrict__ r2h, const unsigned short* __restrict__ r2l,
    const float* __restrict__ r2b) {
    __shared__ unsigned short XsA[128 * 136];
    __shared__ unsigned short XsB[128 * 136];
    int tid = threadIdx.x, bm = blockIdx.x * 128;
    int wid = tid >> 6, lane = tid & 63;
    int wr = wid >> 2, wc = wid & 3;
    int r16 = lane & 15, kg = lane >> 4;
    int arow0 = wr * 64, bcol0 = wc * 32;

    // stage seg (128x64 fp32) -> A
    #pragma unroll
    for (int p = 0; p < 4; p++) {
        int idx = tid + p * 512, row = idx >> 4, cg = idx & 15;
        float4 v = *(const float4*)&seg[(size_t)(bm + row) * 64 + cg * 4];
        *(uint2*)&XsA[row * 136 + cg * 4] = pk4(v.x, v.y, v.z, v.w);
    }
    __syncthreads();

    f32x4 acc[4][2], res[4][2];

    auto store_frags = [&](unsigned short* Xd, const f32x4 (&v)[4][2]) {
        #pragma unroll
        for (int s = 0; s < 4; s++)
            #pragma unroll
            for (int ns = 0; ns < 2; ns++)
                *(uint2*)&Xd[(arow0 + s * 16 + r16) * 136 + bcol0 + ns * 16 + kg * 4] =
                    pk4(v[s][ns][0], v[s][ns][1], v[s][ns][2], v[s][ns][3]);
    };
    auto store_act = [&](unsigned short* Xd, const f32x4 (&a)[4][2], const float* bb) {
        #pragma unroll
        for (int s = 0; s < 4; s++)
            #pragma unroll
            for (int ns = 0; ns < 2; ns++) {
                int n0 = bcol0 + ns * 16 + kg * 4;
                float4 b4 = *(const float4*)&bb[n0];
                *(uint2*)&Xd[(arow0 + s * 16 + r16) * 136 + n0] =
                    pk4(silu_f(a[s][ns][0] + b4.x), silu_f(a[s][ns][1] + b4.y),
                        silu_f(a[s][ns][2] + b4.z), silu_f(a[s][ns][3] + b4.w));
            }
    };
    auto accum_res = [&](const f32x4 (&a)[4][2], const float* bb) {
        #pragma unroll
        for (int s = 0; s < 4; s++)
            #pragma unroll
            for (int ns = 0; ns < 2; ns++) {
                int n0 = bcol0 + ns * 16 + kg * 4;
                float4 b4 = *(const float4*)&bb[n0];
                res[s][ns][0] += silu_f(a[s][ns][0] + b4.x);
                res[s][ns][1] += silu_f(a[s][ns][1] + b4.y);
                res[s][ns][2] += silu_f(a[s][ns][2] + b4.z);
                res[s][ns][3] += silu_f(a[s][ns][3] + b4.w);
            }
    };

    // ---- up: read A, res = xji + silu(acc), write B
    mfma_stage_pp<2, 4, 2, 136>(XsA, uph, upl, 64, arow0, bcol0, r16, kg, acc);
    #pragma unroll
    for (int s = 0; s < 4; s++) {
        int mm = bm + arow0 + s * 16 + r16;
        #pragma unroll
        for (int ns = 0; ns < 2; ns++) {
            int n0 = bcol0 + ns * 16 + kg * 4;
            float4 xv = *(const float4*)&xji[(size_t)mm * 128 + n0];
            res[s][ns][0] = silu_f(acc[s][ns][0]) + xv.x;
            res[s][ns][1] = silu_f(acc[s][ns][1]) + xv.y;
            res[s][ns][2] = silu_f(acc[s][ns][2]) + xv.z;
            res[s][ns][3] = silu_f(acc[s][ns][3]) + xv.w;
        }
    }
    store_frags(XsB, res);
    __syncthreads();

    // ---- res1 a: read B, write A
    mfma_stage_pp<4, 4, 2, 136>(XsB, r1h, r1l, 128, arow0, bcol0, r16, kg, acc);
    store_act(XsA, acc, r1b);
    __syncthreads();
    // ---- res1 b: read A, res +=, write B
    mfma_stage_pp<4, 4, 2, 136>(XsA, r1h + 16384, r1l + 16384, 128, arow0, bcol0, r16, kg, acc);
    accum_res(acc, r1b + 128);
    store_frags(XsB, res);
    __syncthreads();

    // ---- skip: read B, res = silu(acc+b) + m, write A
    mfma_stage_pp<4, 4, 2, 136>(XsB, skh, skl, 128, arow0, bcol0, r16, kg, acc);
    #pragma unroll
    for (int s = 0; s < 4; s++) {
        int mm = bm + arow0 + s * 16 + r16;
        #pragma unroll
        for (int ns = 0; ns < 2; ns++) {
            int n0 = bcol0 + ns * 16 + kg * 4;
            float4 b4 = *(const float4*)&skb[n0];
            float4 mv = *(const float4*)&m[(size_t)mm * 128 + n0];
            res[s][ns][0] = silu_f(acc[s][ns][0] + b4.x) + mv.x;
            res[s][ns][1] = silu_f(acc[s][ns][1] + b4.y) + mv.y;
            res[s][ns][2] = silu_f(acc[s][ns][2] + b4.z) + mv.z;
            res[s][ns][3] = silu_f(acc[s][ns][3] + b4.w) + mv.w;
        }
    }
    store_frags(XsA, res);
    __syncthreads();

    // ---- res2[0] a: read A, write B
    mfma_stage_pp<4, 4, 2, 136>(XsA, r2h, r2l, 128, arow0, bcol0, r16, kg, acc);
    store_act(XsB, acc, r2b);
    __syncthreads();
    // ---- res2[0] b: read B, res +=, write A
    mfma_stage_pp<4, 4, 2, 136>(XsB, r2h + 16384, r2l + 16384, 128, arow0, bcol0, r16, kg, acc);
    accum_res(acc, r2b + 128);
    store_frags(XsA, res);
    __syncthreads();
    // ---- res2[1] a: read A, write B
    mfma_stage_pp<4, 4, 2, 136>(XsA, r2h + 32768, r2l + 32768, 128, arow0, bcol0, r16, kg, acc);
    store_act(XsB, acc, r2b + 256);
    __syncthreads();
    // ---- res2[1] b: read B, res +=, write m
    mfma_stage_pp<4, 4, 2, 136>(XsB, r2h + 49152, r2l + 49152, 128, arow0, bcol0, r16, kg, acc);
    accum_res(acc, r2b + 384);
    #pragma unroll
    for (int s = 0; s < 4; s++) {
        int mm = bm + arow0 + s * 16 + r16;
        #pragma unroll
        for (int ns = 0; ns < 2; ns++) {
            int n0 = bcol0 + ns * 16 + kg * 4;
            float4 o;
            o.x = res[s][ns][0]; o.y = res[s][ns][1];
            o.z = res[s][ns][2]; o.w = res[s][ns][3];
            *(float4*)&m[(size_t)mm * 128 + n0] = o;
        }
    }
}

// ------------------------------- output block scatter: atom += seg(rbfw * m)
__global__ __launch_bounds__(256) void outseg_kernel(
    const float* __restrict__ rbf, const float* __restrict__ orw,
    const float* __restrict__ m, const int* __restrict__ idx_i,
    float* __restrict__ atom) {
    int gid = blockIdx.x * 256 + threadIdx.x;
    int e = gid >> 7, c = gid & 127;
    float s = 0.f;
    #pragma unroll
    for (int k = 0; k < 6; k++) s += rbf[e * 6 + k] * orw[k * 128 + c];
    atomicAdd(&atom[(size_t)idx_i[e] * 128 + c], s * m[gid]);
}

// ===================== triplet phase: counting sort by reduce_to_ji =======
__global__ __launch_bounds__(256) void hist_kernel(const int* __restrict__ rji,
                                                   int* __restrict__ hist) {
    int t = blockIdx.x * 256 + threadIdx.x;
    atomicAdd(&hist[rji[t]], 1);
}

__global__ __launch_bounds__(256) void scan1_kernel(const int* __restrict__ hist,
                                                    int* __restrict__ bsum) {
    __shared__ int s[256];
    int i = threadIdx.x;
    s[i] = hist[blockIdx.x * 256 + i];
    __syncthreads();
    for (int o = 128; o; o >>= 1) {
        if (i < o) s[i] += s[i + o];
        __syncthreads();
    }
    if (!i) bsum[blockIdx.x] = s[0];
}

__global__ __launch_bounds__(256) void scan2_kernel(const int* __restrict__ bsum,
                                                    int* __restrict__ boff) {
    __shared__ int s[256];
    int i = threadIdx.x;
    int own = bsum[i];
    s[i] = own;
    __syncthreads();
    for (int o = 1; o < 256; o <<= 1) {
        int v = (i >= o) ? s[i - o] : 0;
        __syncthreads();
        s[i] += v;
        __syncthreads();
    }
    boff[i] = s[i] - own;
}

__global__ __launch_bounds__(256) void scan3_kernel(const int* __restrict__ hist,
                                                    const int* __restrict__ boff,
                                                    int* __restrict__ rows,
                                                    int* __restrict__ cursor, int T) {
    __shared__ int s[256];
    int i = threadIdx.x, b = blockIdx.x;
    int h = hist[b * 256 + i];
    s[i] = h;
    __syncthreads();
    for (int o = 1; o < 256; o <<= 1) {
        int v = (i >= o) ? s[i - o] : 0;
        __syncthreads();
        s[i] += v;
        __syncthreads();
    }
    int excl = s[i] - h + boff[b];
    rows[b * 256 + i] = excl;
    cursor[b * 256 + i] = excl;
    if (b == gridDim.x - 1 && i == 255) rows[b * 256 + 256] = T;
}

__global__ __launch_bounds__(256) void scatter_kernel(
    const int* __restrict__ rji, const int* __restrict__ ekj,
    int* __restrict__ cursor, int* __restrict__ perm, int* __restrict__ ekjs) {
    int t = blockIdx.x * 256 + threadIdx.x;
    int r = rji[t];
    int pos = atomicAdd(&cursor[r], 1);
    perm[pos] = t;
    ekjs[pos] = ekj[t];
}

// ------------- sbf precompute: trig once, contract with all 4 blocks' sbf1
__global__ __launch_bounds__(256) void sbf_pre_kernel(
    const float* __restrict__ dist, const float* __restrict__ angles,
    const int* __restrict__ perm, const int* __restrict__ ekjs,
    const float* __restrict__ sbf1_all, unsigned short* __restrict__ t32, int T) {
    __shared__ float s1[1344];
    int tid = threadIdx.x;
    for (int i = tid; i < 1344; i += 256) s1[i] = sbf1_all[i];
    __syncthreads();

    int pos = blockIdx.x * 256 + tid;
    int t = perm[pos];
    int e = ekjs[pos];
    float x = fmaxf(dist[e] * 0.2f, 1e-6f);
    float env = 0.f;
    if (x < 1.0f) {
        float x2 = x * x;
        float x5 = x2 * x2 * x;
        env = 1.0f / x + x5 * (-28.0f + x * (48.0f - 21.0f * x));
    }
    float ct = __cosf(angles[t]);
    float Pl[7];
    Pl[0] = 1.f;
    Pl[1] = ct;
    #pragma unroll
    for (int l = 2; l < 7; l++)
        Pl[l] = ((2.f * l - 1.f) * ct * Pl[l - 1] - (l - 1.f) * Pl[l - 2]) / (float)l;
    const float sphc[7] = {0.28209479f, 0.48860251f, 0.63078313f, 0.74635267f,
                           0.84628438f, 0.93560257f, 1.01710723f};
    const float BZ[7][6] = {
        {3.141593f, 6.283185f, 9.424778f, 12.566371f, 15.707963f, 18.849556f},
        {4.493409f, 7.725252f, 10.904122f, 14.066194f, 17.220755f, 20.371303f},
        {5.763459f, 9.095011f, 12.322941f, 15.514603f, 18.689036f, 21.853874f},
        {6.987932f, 10.417119f, 13.698023f, 16.923621f, 20.121806f, 23.304247f},
        {8.182561f, 11.704907f, 15.039665f, 18.301256f, 21.525418f, 24.727566f},
        {9.355812f, 12.966530f, 16.354710f, 19.653152f, 22.904551f, 26.126750f},
        {10.512835f, 14.207392f, 17.647975f, 20.983463f, 24.262768f, 27.507868f}};
    float sbf[42];
    #pragma unroll
    for (int l = 0; l < 7; l++) {
        float coef = env * sphc[l] * Pl[l];
        #pragma unroll
        for (int n = 0; n < 6; n++) {
            float a = BZ[l][n] * x;
            float sa, ca;
            __sincosf(a, &sa, &ca);
            float inv = __builtin_amdgcn_rcpf(a);
            float j;
            if (l == 0) {
                j = sa * inv;
            } else {
                float jm2 = sa * inv;
                float jm1 = (sa * inv - ca) * inv;
                #pragma unroll
                for (int ll = 2; ll <= l; ll++) {
                    float jn = (2.f * ll - 1.f) * inv * jm1 - jm2;
                    jm2 = jm1;
                    jm1 = jn;
                }
                j = jm1;
            }
            sbf[l * 6 + n] = coef * j;
        }
    }
    float acc[32];
    #pragma unroll
    for (int q = 0; q < 32; q++) acc[q] = 0.f;
    #pragma unroll
    for (int k = 0; k < 42; k++) {
        float sv = sbf[k];
        #pragma unroll
        for (int b = 0; b < 4; b++)
            #pragma unroll
            for (int p = 0; p < 8; p++)
                acc[b * 8 + p] = fmaf(sv, s1[b * 336 + k * 8 + p], acc[b * 8 + p]);
    }
    #pragma unroll
    for (int b = 0; b < 4; b++) {
        uint4 u;
        u.x = packbf2(acc[b * 8 + 0], acc[b * 8 + 1]);
        u.y = packbf2(acc[b * 8 + 2], acc[b * 8 + 3]);
        u.z = packbf2(acc[b * 8 + 4], acc[b * 8 + 5]);
        u.w = packbf2(acc[b * 8 + 6], acc[b * 8 + 7]);
        *(uint4*)&t32[((size_t)b * T + pos) * 8] = u;
    }
}

// ------------- per-block gather reduce: one wave per target edge, no atomics
__global__ __launch_bounds__(256) void seg_gather_kernel(
    const unsigned short* __restrict__ t32p, const int* __restrict__ ekjs,
    const int* __restrict__ rows, const float* __restrict__ xdown,
    const float* __restrict__ sbf2, float* __restrict__ seg, int E) {
    int gid = blockIdx.x * 256 + threadIdx.x;
    int e = gid >> 6, lane = gid & 63;
    if (e >= E) return;
    float w2[8];
    #pragma unroll
    for (int p = 0; p < 8; p++) w2[p] = sbf2[p * 64 + lane];
    int p0 = rows[e], p1 = rows[e + 1];
    float acc = 0.f;
    for (int pos = p0; pos < p1; ++pos) {
        uint4 a = *(const uint4*)&t32p[(size_t)pos * 8];
        float v = __uint_as_float(a.x << 16) * w2[0] + __uint_as_float(a.x & 0xffff0000u) * w2[1]
                + __uint_as_float(a.y << 16) * w2[2] + __uint_as_float(a.y & 0xffff0000u) * w2[3]
                + __uint_as_float(a.z << 16) * w2[4] + __uint_as_float(a.z & 0xffff0000u) * w2[5]
                + __uint_as_float(a.w << 16) * w2[6] + __uint_as_float(a.w & 0xffff0000u) * w2[7];
        acc = fmaf(v, xdown[(size_t)ekjs[pos] * 64 + lane], acc);
    }
    seg[(size_t)e * 64 + lane] = acc;
}

// ---------------------------------------------------------------- launcher
extern "C" void kernel_launch(void* const* d_in, const int* in_sizes, int n_in,
                              void* d_out, int out_size, void* d_ws, size_t ws_size,
                              hipStream_t stream) {
    const float* distances   = (const float*)d_in[0];
    const float* angles      = (const float*)d_in[1];
    const float* species_emb = (const float*)d_in[2];
    const float* emb_rbf_w   = (const float*)d_in[3];
    const float* emb_rbf_b   = (const float*)d_in[4];
    const float* emb_dense_w = (const float*)d_in[5];
    const float* emb_dense_b = (const float*)d_in[6];
    const float* out_rbf_w   = (const float*)d_in[7];
    const float* out_up_w    = (const float*)d_in[8];
    const float* out_dense_w = (const float*)d_in[9];
    const float* out_dense_b = (const float*)d_in[10];
    const float* out_final_w = (const float*)d_in[11];
    const float* int_ji_w    = (const float*)d_in[12];
    const float* int_ji_b    = (const float*)d_in[13];
    const float* int_kj_w    = (const float*)d_in[14];
    const float* int_kj_b    = (const float*)d_in[15];
    const float* int_rbf1_w  = (const float*)d_in[16];
    const float* int_rbf2_w  = (const float*)d_in[17];
    const float* int_down_w  = (const float*)d_in[18];
    const float* int_sbf1_w  = (const float*)d_in[19];
    const float* int_sbf2_w  = (const float*)d_in[20];
    const float* int_up_w    = (const float*)d_in[21];
    const float* int_res1_w  = (const float*)d_in[22];
    const float* int_res1_b  = (const float*)d_in[23];
    const float* int_skip_w  = (const float*)d_in[24];
    const float* int_skip_b  = (const float*)d_in[25];
    const float* int_res2_w  = (const float*)d_in[26];
    const float* int_res2_b  = (const float*)d_in[27];
    const int*   species     = (const int*)d_in[28];
    const int*   idx_i       = (const int*)d_in[29];
    const int*   idx_j       = (const int*)d_in[30];
    const int*   reduce_ji   = (const int*)d_in[31];
    const int*   expand_kj   = (const int*)d_in[32];

    const int E = in_sizes[0];       // 65536
    const int T = in_sizes[1];       // 524288
    const int NA = in_sizes[28];     // 4096

    float* ws = (float*)d_ws;
    size_t off = 0;
    float* rbf = ws + off;   off += (size_t)E * 6;
    float* m   = ws + off;   off += (size_t)E * 128;
    float* A   = ws + off;   off += (size_t)E * 128;   // x_ji
    float* B   = ws + off;   off += (size_t)E * 128;   // seg (E x 64 used)
    float* C   = ws + off;   off += (size_t)E * 128;   // spare
    float* D   = ws + off;   off += (size_t)E * 64;    // xdown
    float* HWj = ws + off;   off += 16 * 128;
    float* HWi = ws + off;   off += 16 * 128;
    float* W3  = ws + off;   off += 6 * 128;
    float* b3  = ws + off;   off += 128;
    float* atom1 = ws + off; off += (size_t)NA * 128;
    float* atom2 = ws + off; off += (size_t)NA * 256;
    float* atom3 = ws + off; off += (size_t)NA * 256;
    float* seg = B;

    unsigned short* wb = (unsigned short*)(ws + off);
    size_t wo = 0;
    unsigned short* ji_h = wb + wo;  wo += 4 * 16384;
    unsigned short* ji_l = wb + wo;  wo += 4 * 16384;
    unsigned short* kj_h = wb + wo;  wo += 4 * 16384;
    unsigned short* kj_l = wb + wo;  wo += 4 * 16384;
    unsigned short* dn_h = wb + wo;  wo += 4 * 8192;
    unsigned short* dn_l = wb + wo;  wo += 4 * 8192;
    unsigned short* up_h = wb + wo;  wo += 4 * 8192;
    unsigned short* up_l = wb + wo;  wo += 4 * 8192;
    unsigned short* r1_h = wb + wo;  wo += 8 * 16384;
    unsigned short* r1_l = wb + wo;  wo += 8 * 16384;
    unsigned short* sk_h = wb + wo;  wo += 4 * 16384;
    unsigned short* sk_l = wb + wo;  wo += 4 * 16384;
    unsigned short* r2_h = wb + wo;  wo += 16 * 16384;
    unsigned short* r2_l = wb + wo;  wo += 16 * 16384;
    unsigned short* ou_h = wb + wo;  wo += 5 * 32768;
    unsigned short* ou_l = wb + wo;  wo += 5 * 32768;
    unsigned short* od_h = wb + wo;  wo += 15 * 65536;
    unsigned short* od_l = wb + wo;  wo += 15 * 65536;
    unsigned short* t32 = wb + wo;   wo += (size_t)4 * T * 8;
    int* ip    = (int*)(wb + wo);
    size_t io  = 0;
    int* hist   = ip + io;  io += E;
    int* rows   = ip + io;  io += E + 64;
    int* cursor = ip + io;  io += E;
    int* bsum   = ip + io;  io += 256;
    int* boff   = ip + io;  io += 256;
    int* perm   = ip + io;  io += T;
    int* ekjs   = ip + io;  io += T;

    float* out = (float*)d_out;
    hipMemsetAsync(out, 0, (size_t)out_size * sizeof(float), stream);

    // ---- triplet counting sort + basis precompute (once per launch)
    hipMemsetAsync(hist, 0, (size_t)E * sizeof(int), stream);
    hist_kernel<<<T / 256, 256, 0, stream>>>(reduce_ji, hist);
    scan1_kernel<<<E / 256, 256, 0, stream>>>(hist, bsum);
    scan2_kernel<<<1, 256, 0, stream>>>(bsum, boff);
    scan3_kernel<<<E / 256, 256, 0, stream>>>(hist, boff, rows, cursor, T);
    scatter_kernel<<<T / 256, 256, 0, stream>>>(reduce_ji, expand_kj, cursor, perm, ekjs);
    sbf_pre_kernel<<<T / 256, 256, 0, stream>>>(distances, angles, perm, ekjs,
                                                int_sbf1_w, t32, T);

    // weight conversion (once per launch)
    wconv_kernel<<<dim3(4, 4, 4), 256, 0, stream>>>(int_ji_w, ji_h, ji_l, 128, 128);
    wconv_kernel<<<dim3(4, 4, 4), 256, 0, stream>>>(int_kj_w, kj_h, kj_l, 128, 128);
    wconv_kernel<<<dim3(2, 4, 4), 256, 0, stream>>>(int_down_w, dn_h, dn_l, 128, 64);
    wconv_kernel<<<dim3(4, 2, 4), 256, 0, stream>>>(int_up_w, up_h, up_l, 64, 128);
    wconv_kernel<<<dim3(4, 4, 8), 256, 0, stream>>>(int_res1_w, r1_h, r1_l, 128, 128);
    wconv_kernel<<<dim3(4, 4, 4), 256, 0, stream>>>(int_skip_w, sk_h, sk_l, 128, 128);
    wconv_kernel<<<dim3(4, 4, 16), 256, 0, stream>>>(int_res2_w, r2_h, r2_l, 128, 128);
    wconv_kernel<<<dim3(8, 4, 5), 256, 0, stream>>>(out_up_w, ou_h, ou_l, 128, 256);
    wconv_kernel<<<dim3(8, 8, 15), 256, 0, stream>>>(out_dense_w, od_h, od_l, 256, 256);

    rbf_kernel<<<E / 256, 256, 0, stream>>>(distances, rbf, E);
    embed_pre_kernel<<<1, 128, 0, stream>>>(species_emb, emb_rbf_w, emb_rbf_b,
                                            emb_dense_w, HWj, HWi, W3, b3);
    // block-0 outseg fused into embed (coalesced atomics: lanes = consecutive c)
    hipMemsetAsync(atom1, 0, (size_t)NA * 128 * sizeof(float), stream);
    embed_kernel<<<E * 128 / 256, 256, 0, stream>>>(rbf, species, idx_i, idx_j,
                                                    HWj, HWi, W3, b3, emb_dense_b,
                                                    out_rbf_w, m, atom1);

    auto outtail = [&](int i) {
        mfma_gemmT<0, 0, 0><<<dim3(NA / 64, 2), 512, 0, stream>>>(
            atom1, ou_h + (size_t)i * 32768, ou_l + (size_t)i * 32768,
            nullptr, nullptr, atom2, NA, 128, 256);
        outchain_kernel<<<NA / 64, 512, 0, stream>>>(
            atom2, od_h + (size_t)i * 3 * 65536, od_l + (size_t)i * 3 * 65536,
            out_dense_b + (size_t)i * 3 * 256, out_final_w + (size_t)i * 256, out);
    };

    outtail(0);

    for (int i = 0; i < 4; i++) {
        downpath_kernel<<<E / 128, 512, 0, stream>>>(
            m, rbf, int_rbf1_w + (size_t)i * 48, int_rbf2_w + (size_t)i * 1024,
            ji_h + (size_t)i * 16384, ji_l + (size_t)i * 16384, int_ji_b + (size_t)i * 128,
            kj_h + (size_t)i * 16384, kj_l + (size_t)i * 16384, int_kj_b + (size_t)i * 128,
            dn_h + (size_t)i * 8192, dn_l + (size_t)i * 8192,
            A, D);
        seg_gather_kernel<<<E * 64 / 256, 256, 0, stream>>>(
            t32 + (size_t)i * T * 8, ekjs, rows, D,
            int_sbf2_w + (size_t)i * 8 * 64, seg, E);
        chain_kernel<<<E / 128, 512, 0, stream>>>(
            seg, A, m,
            up_h + (size_t)i * 8192, up_l + (size_t)i * 8192,
            r1_h + (size_t)i * 32768, r1_l + (size_t)i * 32768, int_res1_b + (size_t)i * 256,
            sk_h + (size_t)i * 16384, sk_l + (size_t)i * 16384, int_skip_b + (size_t)i * 128,
            r2_h + (size_t)i * 65536, r2_l + (size_t)i * 65536, int_res2_b + (size_t)i * 512);
        // separate coalesced outseg for block i+1
        hipMemsetAsync(atom1, 0, (size_t)NA * 128 * sizeof(float), stream);
        outseg_kernel<<<E * 128 / 256, 256, 0, stream>>>(
            rbf, out_rbf_w + (size_t)(i + 1) * 768, m, idx_i, atom1);
        outtail(i + 1);
    }
}